// Round 14
// baseline (114.534 us; speedup 1.0000x reference)
//
#include <hip/hip_runtime.h>

// Quanvolution: 8x1x128x128 input, K=3, STRIDE=2 -> 63x63 patches per image,
// 9-qubit statevector sim per patch, output (8, 9, 63, 63) PauliZ expvals.
//
// Layout: one wave per patch; 8 complex amps/lane. Amp index bits:
// [2:0]=reg slot, [8:3]=lane.
//
// R14 vs R13 (passed, 60.1 us steady): the kernel is DS-pipe-bound
// (~231 DS/wave x ~5cyc x 124 waves/CU ~= 95% of the 144k-cyc budget; VALU
// at 76%). Move xor-1 / xor-2 lane shuffles off the DS pipe onto VALU with
// DPP quad_perm (ctrl 0xB1 = [1,0,3,2] = xor1, 0x4E = [2,3,0,1] = xor2):
// covers lane qubits 3,4 in all three Y layers (48 DS) and butterfly stages
// 1,2 (18 DS). DS 231 -> 165. Ring bpermutes stay DS (lane-dependent xor
// mask). Everything else identical to R13 (verified algebra: product-state
// build from LDS-staged alpha/beta, D_A, ring1, Y1, D_B, ring2, Y0, D_C,
// ring1, Y1, measurement with final ring2+Omega absorbed).

namespace {

constexpr int OUT_HW = 63;
constexpr int PPB = 4;                                  // waves per block
constexpr int N_PATCH_TOTAL = 8 * OUT_HW * OUT_HW;      // 31752 == 7938 * 4

typedef _Float16 h2 __attribute__((ext_vector_type(2)));
typedef __fp16  hw2 __attribute__((ext_vector_type(2)));

__device__ __forceinline__ int h2i(h2 v) { return __builtin_bit_cast(int, v); }
__device__ __forceinline__ h2  i2h(int v) { return __builtin_bit_cast(h2, v); }
__device__ __forceinline__ h2  swap_h2(h2 v) { return __builtin_shufflevector(v, v, 1, 0); }

__device__ __forceinline__ int bperm_i(int addr, int v) {
    return __builtin_amdgcn_ds_bpermute(addr, v);
}

// xor-shuffle. M==1/2: DPP quad_perm (VALU pipe, no DS). M==4/8/16: ds_swizzle.
// M==32: ds_bpermute.
template<int M>
__device__ __forceinline__ int shfl_i(int v, int lane) {
    if constexpr (M == 1)
        return __builtin_amdgcn_update_dpp(v, v, 0xB1, 0xF, 0xF, false); // [1,0,3,2]
    else if constexpr (M == 2)
        return __builtin_amdgcn_update_dpp(v, v, 0x4E, 0xF, 0xF, false); // [2,3,0,1]
    else if constexpr (M < 32)
        return __builtin_amdgcn_ds_swizzle(v, 0x1F | (M << 10));
    else
        return bperm_i((lane << 2) ^ 128, v);
}
template<int M>
__device__ __forceinline__ float shfl_f(float v, int lane) {
    return __int_as_float(shfl_i<M>(__float_as_int(v), lane));
}

// Reg-reg CNOT renames (verified R5/R9), packed state.
template<int C, int T>
__device__ __forceinline__ void cnot_h(h2 (&a)[8])
{
    constexpr int cm = 1 << C, tm = 1 << T;
    #pragma unroll
    for (int r = 0; r < 8; ++r) {
        if ((r & cm) && !(r & tm)) {
            const int r1 = r | tm;
            const h2 t = a[r]; a[r] = a[r1]; a[r1] = t;
        }
    }
}

// Ring r=1 minus trailing cnot(8,0): (0,1)(1,2) renames;
// (2,3)..(7,8) -> src_lane = lane ^ ((lane&31)<<1) ^ bit2(reg).
__device__ __forceinline__ void ring1_partial_h(h2 (&a)[8], int lane)
{
    cnot_h<0,1>(a);
    cnot_h<1,2>(a);
    const int sA = (lane ^ ((lane & 31) << 1)) << 2;
    const int sB = sA ^ 4;
    #pragma unroll
    for (int r = 0; r < 8; ++r)
        a[r] = i2h(bperm_i((r & 4) ? sB : sA, h2i(a[r])));
}

// Ring r=2 minus trailing cnot(7,0),cnot(8,1): (0,2) rename;
// (1,3)..(6,8) -> src_lane = lane ^ ((lane&15)<<2) ^ bit1 ^ bit2<<1.
__device__ __forceinline__ void ring2_partial_h(h2 (&a)[8], int lane)
{
    cnot_h<0,2>(a);
    const int s0 = (lane ^ ((lane & 15) << 2)) << 2;
    #pragma unroll
    for (int r = 0; r < 8; ++r) {
        const int ad = s0 ^ (((r >> 1) & 1) << 2) ^ (((r >> 2) & 1) << 3);
        a[r] = i2h(bperm_i(ad, h2i(a[r])));
    }
}

// Diagonal phase layer, packed table: per (r,lane): {c,c} and {-s,+s}.
__device__ __forceinline__ void apply_diag_h(h2 (&a)[8],
                                             const int* __restrict__ dtab,
                                             int dbase, int lane)
{
    #pragma unroll
    for (int r = 0; r < 8; ++r) {
        const int idx = (dbase + r * 64 + lane) * 2;
        const h2 cc = i2h(dtab[idx]);
        const h2 ns = i2h(dtab[idx + 1]);
        a[r] = cc * a[r] + ns * swap_h2(a[r]);
    }
}

// RY on reg qubit QM (packed, real coeffs broadcast into both halves).
template<int QM>
__device__ __forceinline__ void regY_h(h2 (&a)[8], h2 A2, h2 B2, h2 C2, h2 D2)
{
    #pragma unroll
    for (int r = 0; r < 8; ++r) {
        if (!(r & QM)) {
            const int r1 = r | QM;
            const h2 x0 = a[r], x1 = a[r1];
            a[r]  = A2 * x0 + B2 * x1;
            a[r1] = C2 * x0 + D2 * x1;
        }
    }
}

// RY on lane qubit LM: out = c2*self + sp2*partner (one b32 move/amp —
// DPP for LM=1,2, ds_swizzle/bpermute otherwise).
template<int LM>
__device__ __forceinline__ void laneY_h(h2 (&a)[8], int lane, h2 c2, h2 sp2)
{
    #pragma unroll
    for (int r = 0; r < 8; ++r) {
        const h2 p = i2h(shfl_i<LM>(h2i(a[r]), lane));
        a[r] = c2 * a[r] + sp2 * p;
    }
}

// Full RY layer. yt: 9 gates x 3 packed ints {cc},{ss},{nss}.
// sw0/sw1: deferred-CNOT column swaps on q0/q1 (verified R5 mechanism).
__device__ __forceinline__ void apply_Y_h(h2 (&a)[8], int lane,
                                          const int* __restrict__ yt,
                                          bool sw0, bool sw1)
{
    {   const int cc = yt[0], ss = yt[1], ns = yt[2];
        regY_h<1>(a, i2h(sw0 ? ns : cc), i2h(sw0 ? cc : ns),
                     i2h(sw0 ? cc : ss), i2h(sw0 ? ss : cc)); }
    {   const int cc = yt[3], ss = yt[4], ns = yt[5];
        regY_h<2>(a, i2h(sw1 ? ns : cc), i2h(sw1 ? cc : ns),
                     i2h(sw1 ? cc : ss), i2h(sw1 ? ss : cc)); }
    {   regY_h<4>(a, i2h(yt[6]), i2h(yt[8]), i2h(yt[7]), i2h(yt[6])); }
    {   laneY_h<1>(a, lane, i2h(yt[9]),  i2h((lane & 1)        ? yt[10] : yt[11])); }
    {   laneY_h<2>(a, lane, i2h(yt[12]), i2h(((lane >> 1) & 1) ? yt[13] : yt[14])); }
    {   laneY_h<4>(a, lane, i2h(yt[15]), i2h(((lane >> 2) & 1) ? yt[16] : yt[17])); }
    {   laneY_h<8>(a, lane, i2h(yt[18]), i2h(((lane >> 3) & 1) ? yt[19] : yt[20])); }
    {   laneY_h<16>(a, lane, i2h(yt[21]), i2h(((lane >> 4) & 1) ? yt[22] : yt[23])); }
    {   laneY_h<32>(a, lane, i2h(yt[24]), i2h(((lane >> 5) & 1) ? yt[25] : yt[26])); }
}

// ---- Precompute (weights-only).
// ws layout (floats): [0..144) rot fp32; ints at ws+144: ytab 54 ints
// (18 gates x {cc,ss,nss}); ints at ws+208: dtab 3*8*64*2 = 3072 ints.
__global__ void precomp_kernel(const float* __restrict__ w, float* __restrict__ ws)
{
    const int tid = threadIdx.x;
    float* rot = ws;
    int* ytab = (int*)(ws + 144);
    int* dtab = (int*)(ws + 208);
    if (tid < 18) {
        const float phi = w[tid*3 + 0], theta = w[tid*3 + 1], omega = w[tid*3 + 2];
        const float ct = cosf(0.5f * theta), st = sinf(0.5f * theta);
        const float apo = 0.5f * (phi + omega), amo = 0.5f * (phi - omega);
        const float ca = cosf(apo), sa = sinf(apo);
        const float cm = cosf(amo), sm = sinf(amo);
        float* m = rot + tid * 8;
        m[0] =  ca * ct; m[1] = -sa * ct;   // u00
        m[2] = -cm * st; m[3] = -sm * st;   // u01
        m[4] =  cm * st; m[5] = -sm * st;   // u10
        m[6] =  ca * ct; m[7] =  sa * ct;   // u11
        h2 cc; cc.x = (_Float16)ct;  cc.y = (_Float16)ct;
        h2 ss; ss.x = (_Float16)st;  ss.y = (_Float16)st;
        h2 ns; ns.x = (_Float16)(-st); ns.y = (_Float16)(-st);
        ytab[tid*3 + 0] = h2i(cc);
        ytab[tid*3 + 1] = h2i(ss);
        ytab[tid*3 + 2] = h2i(ns);
    }
    if (tid < 192) {
        // ring1 pull-back masks (row-update rule; procedure verified vs ring2)
        const int vmask[9] = {0x1FE,0x003,0x007,0x00F,0x01F,0x03F,0x07F,0x0FF,0x1FF};
        // ring2 pull-back masks (HW-verified R4/R5)
        const int wmask[9] = {0x0AB,0x157,0x005,0x00A,0x015,0x02A,0x055,0x0AA,0x155};
        const int d = tid >> 6, lane = tid & 63;
        for (int r = 0; r < 8; ++r) {
            const int p = (lane << 3) | r;
            float ang = 0.f;
            for (int q = 0; q < 9; ++q) {
                if (d == 0) {            // D_A: conj(Phi_l1) through ring1
                    const float lam = -0.5f * w[(9 + q)*3 + 0];
                    ang += (__popc(p & vmask[q]) & 1) ? -lam : lam;
                } else if (d == 1) {     // D_B: conj(Phi_l0) thru ring2 + Omega_l1
                    const float lam = -0.5f * w[q*3 + 0];
                    ang += (__popc(p & wmask[q]) & 1) ? -lam : lam;
                    const float lm2 = -0.5f * w[(9 + q)*3 + 2];
                    ang += ((p >> q) & 1) ? -lm2 : lm2;
                } else {                 // D_C: conj(Phi_l1) thru ring1 + Omega_l0
                    const float lam = -0.5f * w[(9 + q)*3 + 0];
                    ang += (__popc(p & vmask[q]) & 1) ? -lam : lam;
                    const float lm2 = -0.5f * w[q*3 + 2];
                    ang += ((p >> q) & 1) ? -lm2 : lm2;
                }
            }
            const float c = cosf(ang), s = sinf(ang);
            h2 cc;  cc.x = (_Float16)c;    cc.y = (_Float16)c;
            h2 nsp; nsp.x = (_Float16)(-s); nsp.y = (_Float16)s;  // {-s,+s}
            const int idx = ((d*8 + r)*64 + lane)*2;
            dtab[idx + 0] = h2i(cc);
            dtab[idx + 1] = h2i(nsp);
        }
    }
}

// sign-apply: v * (-1)^par
__device__ __forceinline__ float sgn_apply(float v, int par) {
    return __int_as_float(__float_as_int(v) ^ (par << 31));
}

__global__ __launch_bounds__(PPB * 64, 6) void qconv_kernel(
    const float* __restrict__ x,      // (8, 1, 128, 128)
    const float* __restrict__ ws,     // precomp tables
    float* __restrict__ out)          // (8, 9, 63, 63)
{
    const float* rot  = ws;
    const int* ytab = (const int*)(ws + 144);
    const int* dtab = (const int*)(ws + 208);

    const int lane  = threadIdx.x & 63;
    const int wv    = threadIdx.x >> 6;
    const int patch = blockIdx.x * PPB + wv;

    const int b   = patch / (OUT_HW * OUT_HW);
    const int rem = patch - b * (OUT_HW * OUT_HW);
    const int oy  = rem / OUT_HW;
    const int ox  = rem - oy * OUT_HW;

    // ---- Block-distributed alpha/beta prep (wave-uniform work done once).
    __shared__ float abtab[PPB][36];
    {
        const int t = threadIdx.x;
        if (t < PPB * 36) {
            const int tw = t / 36, j = t - tw * 36;
            const int q = j >> 2, comp = j & 3;
            const int tp   = blockIdx.x * PPB + tw;
            const int tb   = tp / (OUT_HW * OUT_HW);
            const int trem = tp - tb * (OUT_HW * OUT_HW);
            const int toy  = trem / OUT_HW;
            const int tox  = trem - toy * OUT_HW;
            const float ang = x[tb * 16384 + (toy * 2 + q / 3) * 128 + (tox * 2 + q % 3)];
            float s, c;
            __sincosf(0.5f * ang, &s, &c);
            const float* R = rot + 8 * q;
            float v;
            if      (comp == 0) v = c*R[0] + s*R[3];
            else if (comp == 1) v = c*R[1] - s*R[2];
            else if (comp == 2) v = c*R[4] + s*R[7];
            else                v = c*R[5] - s*R[6];
            abtab[tw][j] = v;
        }
    }
    __syncthreads();

    float ab[36];
    #pragma unroll
    for (int j = 0; j < 36; ++j) ab[j] = abtab[wv][j];

    // ---- Product state: amp(p) = prod_q (bit_q(p) ? beta_q : alpha_q)
    float ar[8], ai[8];
    {
        float Lr = 1.0f, Li = 0.0f;              // lane factor (qubits 3..8)
        #pragma unroll
        for (int q = 3; q < 9; ++q) {
            const int bit = (lane >> (q - 3)) & 1;
            const float fr = bit ? ab[4*q + 2] : ab[4*q + 0];
            const float fi = bit ? ab[4*q + 3] : ab[4*q + 1];
            const float nr = Lr*fr - Li*fi;
            const float ni = Lr*fi + Li*fr;
            Lr = nr; Li = ni;
        }
        float c01r[4], c01i[4];
        #pragma unroll
        for (int j = 0; j < 4; ++j) {
            const float f0r = (j & 1) ? ab[2] : ab[0];
            const float f0i = (j & 1) ? ab[3] : ab[1];
            const float f1r = (j & 2) ? ab[6] : ab[4];
            const float f1i = (j & 2) ? ab[7] : ab[5];
            c01r[j] = f0r*f1r - f0i*f1i;
            c01i[j] = f0r*f1i + f0i*f1r;
        }
        float hr[4], hi[4];
        #pragma unroll
        for (int j = 0; j < 4; ++j) {
            hr[j] = c01r[j]*Lr - c01i[j]*Li;
            hi[j] = c01r[j]*Li + c01i[j]*Lr;
        }
        #pragma unroll
        for (int r = 0; r < 8; ++r) {
            const float f2r = (r & 4) ? ab[10] : ab[8];
            const float f2i = (r & 4) ? ab[11] : ab[9];
            ar[r] = hr[r & 3]*f2r - hi[r & 3]*f2i;
            ai[r] = hr[r & 3]*f2i + hi[r & 3]*f2r;
        }
    }

    // Pack into fp16 complex {re,im}
    h2 a[8];
    #pragma unroll
    for (int r = 0; r < 8; ++r)
        a[r] = __builtin_bit_cast(h2, __builtin_amdgcn_cvt_pkrtz(ar[r], ai[r]));

    const bool b4 = ((lane >> 4) & 1) != 0;   // amp-index bit 7 (qubit 7)
    const bool b5 = ((lane >> 5) & 1) != 0;   // amp-index bit 8 (qubit 8)

    // U = Y1 R1 D_C Y0 R2 D_B Y1 R1 D_A |build>, measured with ring2 masks.
    apply_diag_h(a, dtab, 0 * 512, lane);             // D_A
    ring1_partial_h(a, lane);                         // cnot(8,0) -> Y q0 swap
    apply_Y_h(a, lane, ytab + 27, b5, false);         // Y(l=1)
    apply_diag_h(a, dtab, 1 * 512, lane);             // D_B
    ring2_partial_h(a, lane);                         // (7,0),(8,1) -> Y q0/q1
    apply_Y_h(a, lane, ytab + 0, b4, b5);             // Y(l=0)
    apply_diag_h(a, dtab, 2 * 512, lane);             // D_C
    ring1_partial_h(a, lane);                         // cnot(8,0) -> Y q0 swap
    apply_Y_h(a, lane, ytab + 27, b5, false);         // Y(l=1)
    // final Omega(l=1) dropped; final ring2 absorbed into masks below.

    // ---- Measurement: e_q = sum_p (-1)^{parity(p & w_q)} |amp_p|^2
    float p[8];
    #pragma unroll
    for (int r = 0; r < 8; ++r) {
#if __has_builtin(__builtin_amdgcn_fdot2)
        p[r] = __builtin_amdgcn_fdot2(__builtin_bit_cast(hw2, a[r]),
                                      __builtin_bit_cast(hw2, a[r]), 0.0f, false);
#else
        const float xr = (float)a[r].x, xi = (float)a[r].y;
        p[r] = xr*xr + xi*xi;
#endif
    }

    const float t03 = p[0]+p[3], t12 = p[1]+p[2], t47 = p[4]+p[7], t56 = p[5]+p[6];
    const float S3 = (t03 + t47) - (t12 + t56);
    const float S7 = (t03 + t56) - (t12 + t47);
    const float u02 = p[0]+p[2], u13 = p[1]+p[3], u57 = p[5]+p[7], u46 = p[4]+p[6];
    const float S5 = (u02 + u57) - (u13 + u46);
    const float v01 = p[0]+p[1], v23 = p[2]+p[3], v45 = p[4]+p[5], v67 = p[6]+p[7];
    const float S2 = (v01 + v45) - (v23 + v67);

    const int c0 = lane & 1, c1 = (lane >> 1) & 1, c2 = (lane >> 2) & 1;
    const int c3 = (lane >> 3) & 1, c4 = (lane >> 4) & 1, c5 = (lane >> 5) & 1;
    const int p05 = c0 ^ c2, p0A = c1 ^ c3;
    const int p15 = p05 ^ c4, p2A = p0A ^ c5;

    float e[9];
    e[0] = sgn_apply(S3, p15);   // w0 = 0x0AB
    e[1] = sgn_apply(S7, p2A);   // w1 = 0x157
    e[2] = S5;                   // w2 = 0x005
    e[3] = sgn_apply(S2, c0);    // w3 = 0x00A
    e[4] = sgn_apply(S5, c1);    // w4 = 0x015
    e[5] = sgn_apply(S2, p05);   // w5 = 0x02A
    e[6] = sgn_apply(S5, p0A);   // w6 = 0x055
    e[7] = sgn_apply(S2, p15);   // w7 = 0x0AA
    e[8] = sgn_apply(S5, p2A);   // w8 = 0x155

    #pragma unroll
    for (int q = 0; q < 9; ++q) e[q] += shfl_f<1>(e[q], lane);   // DPP
    #pragma unroll
    for (int q = 0; q < 9; ++q) e[q] += shfl_f<2>(e[q], lane);   // DPP
    #pragma unroll
    for (int q = 0; q < 9; ++q) e[q] += shfl_f<4>(e[q], lane);
    #pragma unroll
    for (int q = 0; q < 9; ++q) e[q] += shfl_f<8>(e[q], lane);
    #pragma unroll
    for (int q = 0; q < 9; ++q) e[q] += shfl_f<16>(e[q], lane);
    #pragma unroll
    for (int q = 0; q < 9; ++q) e[q] += shfl_f<32>(e[q], lane);

    float v = e[0];
    v = (lane == 1) ? e[1] : v;
    v = (lane == 2) ? e[2] : v;
    v = (lane == 3) ? e[3] : v;
    v = (lane == 4) ? e[4] : v;
    v = (lane == 5) ? e[5] : v;
    v = (lane == 6) ? e[6] : v;
    v = (lane == 7) ? e[7] : v;
    v = (lane == 8) ? e[8] : v;
    if (lane < 9) {
        out[(b * 9 + lane) * (OUT_HW * OUT_HW) + oy * OUT_HW + ox] = v;
    }
}

} // anonymous namespace

extern "C" void kernel_launch(void* const* d_in, const int* in_sizes, int n_in,
                              void* d_out, int out_size, void* d_ws, size_t ws_size,
                              hipStream_t stream)
{
    const float* x = (const float*)d_in[0];   // (8,1,128,128) float32
    const float* w = (const float*)d_in[1];   // (2,9,3) float32
    float* ws = (float*)d_ws;                 // ~3.3k floats scratch
    float* out = (float*)d_out;               // (8,9,63,63) float32

    precomp_kernel<<<1, 256, 0, stream>>>(w, ws);
    qconv_kernel<<<N_PATCH_TOTAL / PPB, PPB * 64, 0, stream>>>(x, ws, out);
}

// Round 15
// 109.553 us; speedup vs baseline: 1.0455x; 1.0455x over previous
//
#include <hip/hip_runtime.h>

// Quanvolution: 8x1x128x128 input, K=3, STRIDE=2 -> 63x63 patches per image,
// 9-qubit statevector sim per patch, output (8, 9, 63, 63) PauliZ expvals.
//
// Layout: one wave per patch; 8 complex amps/lane. Amp index bits:
// [2:0]=reg slot, [8:3]=lane.
//
// R15 vs R14 (66.4 us, regressed) / R13 (60.1 us, best):
//  - REVERT R14's DPP shuffles: CDNA DPP cross-lane reads of just-written
//    VGPRs need hazard wait states (s_nop) on the 76%-busy VALU pipe; the
//    DS swizzles they replaced run on a parallel pipe. All shuffles back to
//    ds_swizzle/ds_bpermute (R13 config).
//  - Measurement butterfly (54 DS) replaced by 4 in-place Walsh-Hadamard
//    transforms (24 DS): all 9 channel outputs are Walsh coefficients of the
//    4 per-lane reg-sums — e[q] = W_{S_m}[L_q]; after the 6-stage WHT
//    (x = partner +/- self per lane-bit) lane L holds coefficient L. Outputs
//    gathered from lanes {0,2,0xA,0x2A}(S5), {1,5,0x15}(S2), 0x15(S3),
//    0x2A(S7) by predicated stores. DS/wave 231 -> 201.
//  - Everything else identical to R13 (verified): LDS-staged alpha/beta,
//    product-state build, D_A, ring1, Y1, D_B, ring2, Y0, D_C, ring1, Y1,
//    final ring2+Omega absorbed in the Walsh masks.

namespace {

constexpr int OUT_HW = 63;
constexpr int PPB = 4;                                  // waves per block
constexpr int N_PATCH_TOTAL = 8 * OUT_HW * OUT_HW;      // 31752 == 7938 * 4

typedef _Float16 h2 __attribute__((ext_vector_type(2)));
typedef __fp16  hw2 __attribute__((ext_vector_type(2)));

__device__ __forceinline__ int h2i(h2 v) { return __builtin_bit_cast(int, v); }
__device__ __forceinline__ h2  i2h(int v) { return __builtin_bit_cast(h2, v); }
__device__ __forceinline__ h2  swap_h2(h2 v) { return __builtin_shufflevector(v, v, 1, 0); }

__device__ __forceinline__ int bperm_i(int addr, int v) {
    return __builtin_amdgcn_ds_bpermute(addr, v);
}

// xor-shuffle: ds_swizzle for mask<32 (no addr VGPR), ds_bpermute for 32.
template<int M>
__device__ __forceinline__ int shfl_i(int v, int lane) {
    if constexpr (M < 32)
        return __builtin_amdgcn_ds_swizzle(v, 0x1F | (M << 10));
    else
        return bperm_i((lane << 2) ^ 128, v);
}
template<int M>
__device__ __forceinline__ float shfl_f(float v, int lane) {
    return __int_as_float(shfl_i<M>(__float_as_int(v), lane));
}

// Reg-reg CNOT renames (verified R5/R9), packed state.
template<int C, int T>
__device__ __forceinline__ void cnot_h(h2 (&a)[8])
{
    constexpr int cm = 1 << C, tm = 1 << T;
    #pragma unroll
    for (int r = 0; r < 8; ++r) {
        if ((r & cm) && !(r & tm)) {
            const int r1 = r | tm;
            const h2 t = a[r]; a[r] = a[r1]; a[r1] = t;
        }
    }
}

// Ring r=1 minus trailing cnot(8,0): (0,1)(1,2) renames;
// (2,3)..(7,8) -> src_lane = lane ^ ((lane&31)<<1) ^ bit2(reg).
__device__ __forceinline__ void ring1_partial_h(h2 (&a)[8], int lane)
{
    cnot_h<0,1>(a);
    cnot_h<1,2>(a);
    const int sA = (lane ^ ((lane & 31) << 1)) << 2;
    const int sB = sA ^ 4;
    #pragma unroll
    for (int r = 0; r < 8; ++r)
        a[r] = i2h(bperm_i((r & 4) ? sB : sA, h2i(a[r])));
}

// Ring r=2 minus trailing cnot(7,0),cnot(8,1): (0,2) rename;
// (1,3)..(6,8) -> src_lane = lane ^ ((lane&15)<<2) ^ bit1 ^ bit2<<1.
__device__ __forceinline__ void ring2_partial_h(h2 (&a)[8], int lane)
{
    cnot_h<0,2>(a);
    const int s0 = (lane ^ ((lane & 15) << 2)) << 2;
    #pragma unroll
    for (int r = 0; r < 8; ++r) {
        const int ad = s0 ^ (((r >> 1) & 1) << 2) ^ (((r >> 2) & 1) << 3);
        a[r] = i2h(bperm_i(ad, h2i(a[r])));
    }
}

// Diagonal phase layer, packed table: per (r,lane): {c,c} and {-s,+s}.
__device__ __forceinline__ void apply_diag_h(h2 (&a)[8],
                                             const int* __restrict__ dtab,
                                             int dbase, int lane)
{
    #pragma unroll
    for (int r = 0; r < 8; ++r) {
        const int idx = (dbase + r * 64 + lane) * 2;
        const h2 cc = i2h(dtab[idx]);
        const h2 ns = i2h(dtab[idx + 1]);
        a[r] = cc * a[r] + ns * swap_h2(a[r]);
    }
}

// RY on reg qubit QM (packed, real coeffs broadcast into both halves).
template<int QM>
__device__ __forceinline__ void regY_h(h2 (&a)[8], h2 A2, h2 B2, h2 C2, h2 D2)
{
    #pragma unroll
    for (int r = 0; r < 8; ++r) {
        if (!(r & QM)) {
            const int r1 = r | QM;
            const h2 x0 = a[r], x1 = a[r1];
            a[r]  = A2 * x0 + B2 * x1;
            a[r1] = C2 * x0 + D2 * x1;
        }
    }
}

// RY on lane qubit LM: out = c2*self + sp2*partner (one b32 shuffle/amp).
template<int LM>
__device__ __forceinline__ void laneY_h(h2 (&a)[8], int lane, h2 c2, h2 sp2)
{
    #pragma unroll
    for (int r = 0; r < 8; ++r) {
        const h2 p = i2h(shfl_i<LM>(h2i(a[r]), lane));
        a[r] = c2 * a[r] + sp2 * p;
    }
}

// Full RY layer. yt: 9 gates x 3 packed ints {cc},{ss},{nss}.
// sw0/sw1: deferred-CNOT column swaps on q0/q1 (verified R5 mechanism).
__device__ __forceinline__ void apply_Y_h(h2 (&a)[8], int lane,
                                          const int* __restrict__ yt,
                                          bool sw0, bool sw1)
{
    {   const int cc = yt[0], ss = yt[1], ns = yt[2];
        regY_h<1>(a, i2h(sw0 ? ns : cc), i2h(sw0 ? cc : ns),
                     i2h(sw0 ? cc : ss), i2h(sw0 ? ss : cc)); }
    {   const int cc = yt[3], ss = yt[4], ns = yt[5];
        regY_h<2>(a, i2h(sw1 ? ns : cc), i2h(sw1 ? cc : ns),
                     i2h(sw1 ? cc : ss), i2h(sw1 ? ss : cc)); }
    {   regY_h<4>(a, i2h(yt[6]), i2h(yt[8]), i2h(yt[7]), i2h(yt[6])); }
    {   laneY_h<1>(a, lane, i2h(yt[9]),  i2h((lane & 1)        ? yt[10] : yt[11])); }
    {   laneY_h<2>(a, lane, i2h(yt[12]), i2h(((lane >> 1) & 1) ? yt[13] : yt[14])); }
    {   laneY_h<4>(a, lane, i2h(yt[15]), i2h(((lane >> 2) & 1) ? yt[16] : yt[17])); }
    {   laneY_h<8>(a, lane, i2h(yt[18]), i2h(((lane >> 3) & 1) ? yt[19] : yt[20])); }
    {   laneY_h<16>(a, lane, i2h(yt[21]), i2h(((lane >> 4) & 1) ? yt[22] : yt[23])); }
    {   laneY_h<32>(a, lane, i2h(yt[24]), i2h(((lane >> 5) & 1) ? yt[25] : yt[26])); }
}

// ---- Precompute (weights-only).
// ws layout (floats): [0..144) rot fp32; ints at ws+144: ytab 54 ints
// (18 gates x {cc,ss,nss}); ints at ws+208: dtab 3*8*64*2 = 3072 ints.
__global__ void precomp_kernel(const float* __restrict__ w, float* __restrict__ ws)
{
    const int tid = threadIdx.x;
    float* rot = ws;
    int* ytab = (int*)(ws + 144);
    int* dtab = (int*)(ws + 208);
    if (tid < 18) {
        const float phi = w[tid*3 + 0], theta = w[tid*3 + 1], omega = w[tid*3 + 2];
        const float ct = cosf(0.5f * theta), st = sinf(0.5f * theta);
        const float apo = 0.5f * (phi + omega), amo = 0.5f * (phi - omega);
        const float ca = cosf(apo), sa = sinf(apo);
        const float cm = cosf(amo), sm = sinf(amo);
        float* m = rot + tid * 8;
        m[0] =  ca * ct; m[1] = -sa * ct;   // u00
        m[2] = -cm * st; m[3] = -sm * st;   // u01
        m[4] =  cm * st; m[5] = -sm * st;   // u10
        m[6] =  ca * ct; m[7] =  sa * ct;   // u11
        h2 cc; cc.x = (_Float16)ct;  cc.y = (_Float16)ct;
        h2 ss; ss.x = (_Float16)st;  ss.y = (_Float16)st;
        h2 ns; ns.x = (_Float16)(-st); ns.y = (_Float16)(-st);
        ytab[tid*3 + 0] = h2i(cc);
        ytab[tid*3 + 1] = h2i(ss);
        ytab[tid*3 + 2] = h2i(ns);
    }
    if (tid < 192) {
        // ring1 pull-back masks (row-update rule; procedure verified vs ring2)
        const int vmask[9] = {0x1FE,0x003,0x007,0x00F,0x01F,0x03F,0x07F,0x0FF,0x1FF};
        // ring2 pull-back masks (HW-verified R4/R5)
        const int wmask[9] = {0x0AB,0x157,0x005,0x00A,0x015,0x02A,0x055,0x0AA,0x155};
        const int d = tid >> 6, lane = tid & 63;
        for (int r = 0; r < 8; ++r) {
            const int p = (lane << 3) | r;
            float ang = 0.f;
            for (int q = 0; q < 9; ++q) {
                if (d == 0) {            // D_A: conj(Phi_l1) through ring1
                    const float lam = -0.5f * w[(9 + q)*3 + 0];
                    ang += (__popc(p & vmask[q]) & 1) ? -lam : lam;
                } else if (d == 1) {     // D_B: conj(Phi_l0) thru ring2 + Omega_l1
                    const float lam = -0.5f * w[q*3 + 0];
                    ang += (__popc(p & wmask[q]) & 1) ? -lam : lam;
                    const float lm2 = -0.5f * w[(9 + q)*3 + 2];
                    ang += ((p >> q) & 1) ? -lm2 : lm2;
                } else {                 // D_C: conj(Phi_l1) thru ring1 + Omega_l0
                    const float lam = -0.5f * w[(9 + q)*3 + 0];
                    ang += (__popc(p & vmask[q]) & 1) ? -lam : lam;
                    const float lm2 = -0.5f * w[q*3 + 2];
                    ang += ((p >> q) & 1) ? -lm2 : lm2;
                }
            }
            const float c = cosf(ang), s = sinf(ang);
            h2 cc;  cc.x = (_Float16)c;    cc.y = (_Float16)c;
            h2 nsp; nsp.x = (_Float16)(-s); nsp.y = (_Float16)s;  // {-s,+s}
            const int idx = ((d*8 + r)*64 + lane)*2;
            dtab[idx + 0] = h2i(cc);
            dtab[idx + 1] = h2i(nsp);
        }
    }
}

// sign-apply: v * (-1)^par
__device__ __forceinline__ float sgn_apply(float v, int par) {
    return __int_as_float(__float_as_int(v) ^ (par << 31));
}

__global__ __launch_bounds__(PPB * 64, 6) void qconv_kernel(
    const float* __restrict__ x,      // (8, 1, 128, 128)
    const float* __restrict__ ws,     // precomp tables
    float* __restrict__ out)          // (8, 9, 63, 63)
{
    const float* rot  = ws;
    const int* ytab = (const int*)(ws + 144);
    const int* dtab = (const int*)(ws + 208);

    const int lane  = threadIdx.x & 63;
    const int wv    = threadIdx.x >> 6;
    const int patch = blockIdx.x * PPB + wv;

    const int b   = patch / (OUT_HW * OUT_HW);
    const int rem = patch - b * (OUT_HW * OUT_HW);
    const int oy  = rem / OUT_HW;
    const int ox  = rem - oy * OUT_HW;

    // ---- Block-distributed alpha/beta prep (wave-uniform work done once).
    __shared__ float abtab[PPB][36];
    {
        const int t = threadIdx.x;
        if (t < PPB * 36) {
            const int tw = t / 36, j = t - tw * 36;
            const int q = j >> 2, comp = j & 3;
            const int tp   = blockIdx.x * PPB + tw;
            const int tb   = tp / (OUT_HW * OUT_HW);
            const int trem = tp - tb * (OUT_HW * OUT_HW);
            const int toy  = trem / OUT_HW;
            const int tox  = trem - toy * OUT_HW;
            const float ang = x[tb * 16384 + (toy * 2 + q / 3) * 128 + (tox * 2 + q % 3)];
            float s, c;
            __sincosf(0.5f * ang, &s, &c);
            const float* R = rot + 8 * q;
            float v;
            if      (comp == 0) v = c*R[0] + s*R[3];
            else if (comp == 1) v = c*R[1] - s*R[2];
            else if (comp == 2) v = c*R[4] + s*R[7];
            else                v = c*R[5] - s*R[6];
            abtab[tw][j] = v;
        }
    }
    __syncthreads();

    float ab[36];
    #pragma unroll
    for (int j = 0; j < 36; ++j) ab[j] = abtab[wv][j];

    // ---- Product state: amp(p) = prod_q (bit_q(p) ? beta_q : alpha_q)
    float ar[8], ai[8];
    {
        float Lr = 1.0f, Li = 0.0f;              // lane factor (qubits 3..8)
        #pragma unroll
        for (int q = 3; q < 9; ++q) {
            const int bit = (lane >> (q - 3)) & 1;
            const float fr = bit ? ab[4*q + 2] : ab[4*q + 0];
            const float fi = bit ? ab[4*q + 3] : ab[4*q + 1];
            const float nr = Lr*fr - Li*fi;
            const float ni = Lr*fi + Li*fr;
            Lr = nr; Li = ni;
        }
        float c01r[4], c01i[4];
        #pragma unroll
        for (int j = 0; j < 4; ++j) {
            const float f0r = (j & 1) ? ab[2] : ab[0];
            const float f0i = (j & 1) ? ab[3] : ab[1];
            const float f1r = (j & 2) ? ab[6] : ab[4];
            const float f1i = (j & 2) ? ab[7] : ab[5];
            c01r[j] = f0r*f1r - f0i*f1i;
            c01i[j] = f0r*f1i + f0i*f1r;
        }
        float hr[4], hi[4];
        #pragma unroll
        for (int j = 0; j < 4; ++j) {
            hr[j] = c01r[j]*Lr - c01i[j]*Li;
            hi[j] = c01r[j]*Li + c01i[j]*Lr;
        }
        #pragma unroll
        for (int r = 0; r < 8; ++r) {
            const float f2r = (r & 4) ? ab[10] : ab[8];
            const float f2i = (r & 4) ? ab[11] : ab[9];
            ar[r] = hr[r & 3]*f2r - hi[r & 3]*f2i;
            ai[r] = hr[r & 3]*f2i + hi[r & 3]*f2r;
        }
    }

    // Pack into fp16 complex {re,im}
    h2 a[8];
    #pragma unroll
    for (int r = 0; r < 8; ++r)
        a[r] = __builtin_bit_cast(h2, __builtin_amdgcn_cvt_pkrtz(ar[r], ai[r]));

    const bool b4 = ((lane >> 4) & 1) != 0;   // amp-index bit 7 (qubit 7)
    const bool b5 = ((lane >> 5) & 1) != 0;   // amp-index bit 8 (qubit 8)

    // U = Y1 R1 D_C Y0 R2 D_B Y1 R1 D_A |build>, measured with ring2 masks.
    apply_diag_h(a, dtab, 0 * 512, lane);             // D_A
    ring1_partial_h(a, lane);                         // cnot(8,0) -> Y q0 swap
    apply_Y_h(a, lane, ytab + 27, b5, false);         // Y(l=1)
    apply_diag_h(a, dtab, 1 * 512, lane);             // D_B
    ring2_partial_h(a, lane);                         // (7,0),(8,1) -> Y q0/q1
    apply_Y_h(a, lane, ytab + 0, b4, b5);             // Y(l=0)
    apply_diag_h(a, dtab, 2 * 512, lane);             // D_C
    ring1_partial_h(a, lane);                         // cnot(8,0) -> Y q0 swap
    apply_Y_h(a, lane, ytab + 27, b5, false);         // Y(l=1)
    // final Omega(l=1) dropped; final ring2 absorbed into the Walsh masks.

    // ---- Measurement: e_q = sum_p (-1)^{parity(p & w_q)} |amp_p|^2
    float p[8];
    #pragma unroll
    for (int r = 0; r < 8; ++r) {
#if __has_builtin(__builtin_amdgcn_fdot2)
        p[r] = __builtin_amdgcn_fdot2(__builtin_bit_cast(hw2, a[r]),
                                      __builtin_bit_cast(hw2, a[r]), 0.0f, false);
#else
        const float xr = (float)a[r].x, xi = (float)a[r].y;
        p[r] = xr*xr + xi*xi;
#endif
    }

    // 4 signed register sums (reg masks 3,7,5,2 of the w_q)
    const float t03 = p[0]+p[3], t12 = p[1]+p[2], t47 = p[4]+p[7], t56 = p[5]+p[6];
    float S3 = (t03 + t47) - (t12 + t56);
    float S7 = (t03 + t56) - (t12 + t47);
    const float u02 = p[0]+p[2], u13 = p[1]+p[3], u57 = p[5]+p[7], u46 = p[4]+p[6];
    float S5 = (u02 + u57) - (u13 + u46);
    const float v01 = p[0]+p[1], v23 = p[2]+p[3], v45 = p[4]+p[5], v67 = p[6]+p[7];
    float S2 = (v01 + v45) - (v23 + v67);

    // ---- 4 simultaneous Walsh-Hadamard transforms over the 64 lanes.
    // Stage k: x = partner + (bit_k(lane) ? -x : x). After all 6 stages,
    // lane L holds W[L] = sum_l (-1)^{parity(L&l)} x_l.
    const int sm0 = (lane & 1) << 31;
    const int sm1 = ((lane >> 1) & 1) << 31;
    const int sm2 = ((lane >> 2) & 1) << 31;
    const int sm3 = ((lane >> 3) & 1) << 31;
    const int sm4 = ((lane >> 4) & 1) << 31;
    const int sm5 = ((lane >> 5) & 1) << 31;
#define WHT_STAGE(M, SM) { \
    const float q3 = shfl_f<M>(S3, lane), q7 = shfl_f<M>(S7, lane); \
    const float q5 = shfl_f<M>(S5, lane), q2 = shfl_f<M>(S2, lane); \
    S3 = q3 + __int_as_float(__float_as_int(S3) ^ (SM)); \
    S7 = q7 + __int_as_float(__float_as_int(S7) ^ (SM)); \
    S5 = q5 + __int_as_float(__float_as_int(S5) ^ (SM)); \
    S2 = q2 + __int_as_float(__float_as_int(S2) ^ (SM)); }
    WHT_STAGE(1,  sm0)
    WHT_STAGE(2,  sm1)
    WHT_STAGE(4,  sm2)
    WHT_STAGE(8,  sm3)
    WHT_STAGE(16, sm4)
    WHT_STAGE(32, sm5)
#undef WHT_STAGE

    // ---- Gather: channel q lives in lane L_q of its S's WHT.
    // S5: e2@0x00, e4@0x02, e6@0x0A, e8@0x2A | S2: e3@0x01, e5@0x05, e7@0x15
    // S3: e0@0x15 | S7: e1@0x2A
    const int base = b * 9;
    const int pix  = oy * OUT_HW + ox;
    int chA = -1; float vA = 0.f;
    if (lane == 0x00) { chA = 2; vA = S5; }
    if (lane == 0x02) { chA = 4; vA = S5; }
    if (lane == 0x0A) { chA = 6; vA = S5; }
    if (lane == 0x2A) { chA = 8; vA = S5; }
    if (lane == 0x01) { chA = 3; vA = S2; }
    if (lane == 0x05) { chA = 5; vA = S2; }
    if (lane == 0x15) { chA = 7; vA = S2; }
    if (chA >= 0)
        out[(base + chA) * (OUT_HW * OUT_HW) + pix] = vA;
    if (lane == 0x15)
        out[(base + 0) * (OUT_HW * OUT_HW) + pix] = S3;
    if (lane == 0x2A)
        out[(base + 1) * (OUT_HW * OUT_HW) + pix] = S7;
}

} // anonymous namespace

extern "C" void kernel_launch(void* const* d_in, const int* in_sizes, int n_in,
                              void* d_out, int out_size, void* d_ws, size_t ws_size,
                              hipStream_t stream)
{
    const float* x = (const float*)d_in[0];   // (8,1,128,128) float32
    const float* w = (const float*)d_in[1];   // (2,9,3) float32
    float* ws = (float*)d_ws;                 // ~3.3k floats scratch
    float* out = (float*)d_out;               // (8,9,63,63) float32

    precomp_kernel<<<1, 256, 0, stream>>>(w, ws);
    qconv_kernel<<<N_PATCH_TOTAL / PPB, PPB * 64, 0, stream>>>(x, ws, out);
}